// Round 9
// baseline (328.227 us; speedup 1.0000x reference)
//
#include <hip/hip_runtime.h>
#include <hip/hip_bf16.h>

#define NN 320
#define CC 128
#define HH 4
#define CHD 32
#define HC 128
#define NP (NN*NN)

typedef __hip_bfloat16 bf16;
typedef __bf16 bfv8 __attribute__((ext_vector_type(8)));
typedef short bsv4 __attribute__((ext_vector_type(4)));
typedef float fv4 __attribute__((ext_vector_type(4)));

__device__ __forceinline__ unsigned short bfbits(float f) {
    bf16 h = __float2bfloat16(f);
    return *reinterpret_cast<unsigned short*>(&h);
}

// 16x16x16 bf16 MFMA (K=16): B-frag layout B[k=4g+i][n=c] matches the QK
// D-layout S[k=4g+r][q=c] exactly -> P feeds PV straight from registers.
// NOTE: inline asm => LLVM's hazard recognizer cannot guard the dest; any
// VALU read of the accumulator must be pinned behind an s_nop guard.
__device__ __forceinline__ fv4 mfma16x16x16(bsv4 a, bsv4 b, fv4 c) {
    asm("v_mfma_f32_16x16x16_bf16 %0, %1, %2, %0" : "+v"(c) : "v"(a), "v"(b));
    return c;
}

// ---------------- K0: weight convert/transpose to bf16 ----------------
__global__ __launch_bounds__(256) void k_wconv(
    const float* __restrict__ wq, const float* __restrict__ wk,
    const float* __restrict__ wv, const float* __restrict__ wg,
    const float* __restrict__ wo, const float* __restrict__ w_bias,
    bf16* __restrict__ wt, bf16* __restrict__ wot, bf16* __restrict__ wtb)
{
    __shared__ unsigned short T[128 * 136];
    const int b = blockIdx.x, t = threadIdx.x;
    if (b < 5) {
        const float* W = (b == 0) ? wq : (b == 1) ? wk : (b == 2) ? wv : (b == 3) ? wg : wo;
        bf16* D = (b < 4) ? (wt + b * 16384) : wot;
        const float scale = (b == 0) ? 0.17677669529663687f : 1.0f;
        for (int idx = t; idx < 16384; idx += 256) {
            int c = idx >> 7, out = idx & 127;
            T[out * 136 + c] = bfbits(W[idx] * scale);
        }
        __syncthreads();
        for (int i8 = t; i8 < 2048; i8 += 256) {
            int out = i8 >> 4, c0 = (i8 & 15) * 8;
            uint4 v = *reinterpret_cast<const uint4*>(&T[out * 136 + c0]);
            *reinterpret_cast<uint4*>(D + out * 128 + c0) = v;
        }
    } else {
        int out = t >> 4, c0 = (t & 15) * 8;
        unsigned short vals[8];
#pragma unroll
        for (int j = 0; j < 8; j++)
            vals[j] = (out < 4) ? bfbits(w_bias[(c0 + j) * 4 + out]) : (unsigned short)0;
        *reinterpret_cast<uint4*>(wtb + out * 128 + c0) = *reinterpret_cast<uint4*>(vals);
    }
}

// ---------------- K1a: LayerNorm -> bf16, materialized once ----------------
// Pure streaming: no LDS, no barriers. 1600 blocks x 64 pixels.
__global__ __launch_bounds__(256) void k_ln(
    const float* __restrict__ x, const float* __restrict__ ln_g, const float* __restrict__ ln_b,
    bf16* __restrict__ lnb)
{
    const int t = threadIdx.x;
    const int p = blockIdx.x * 64 + (t >> 2), l = t & 3;
    const float* xr = x + (size_t)p * CC + l * 32;
    float4 xv[8];
#pragma unroll
    for (int i = 0; i < 8; i++) xv[i] = reinterpret_cast<const float4*>(xr)[i];
    float s = 0.f, s2 = 0.f;
#pragma unroll
    for (int i = 0; i < 8; i++) {
        s  += xv[i].x + xv[i].y + xv[i].z + xv[i].w;
        s2 += xv[i].x * xv[i].x + xv[i].y * xv[i].y + xv[i].z * xv[i].z + xv[i].w * xv[i].w;
    }
    s  += __shfl_xor(s, 1, 4);  s  += __shfl_xor(s, 2, 4);
    s2 += __shfl_xor(s2, 1, 4); s2 += __shfl_xor(s2, 2, 4);
    float mu = s * (1.f / CC);
    float var = s2 * (1.f / CC) - mu * mu;
    float rstd = rsqrtf(var + 1e-5f);
    const float4* gr = reinterpret_cast<const float4*>(ln_g + l * 32);
    const float4* br = reinterpret_cast<const float4*>(ln_b + l * 32);
    bf16* dst = lnb + (size_t)p * CC + l * 32;
#pragma unroll
    for (int i = 0; i < 8; i += 2) {
        float4 g0 = gr[i], g1 = gr[i + 1], b0 = br[i], b1 = br[i + 1];
        uint4 pk;
        pk.x = (unsigned)bfbits((xv[i].x - mu) * rstd * g0.x + b0.x)
             | ((unsigned)bfbits((xv[i].y - mu) * rstd * g0.y + b0.y) << 16);
        pk.y = (unsigned)bfbits((xv[i].z - mu) * rstd * g0.z + b0.z)
             | ((unsigned)bfbits((xv[i].w - mu) * rstd * g0.w + b0.w) << 16);
        pk.z = (unsigned)bfbits((xv[i+1].x - mu) * rstd * g1.x + b1.x)
             | ((unsigned)bfbits((xv[i+1].y - mu) * rstd * g1.y + b1.y) << 16);
        pk.w = (unsigned)bfbits((xv[i+1].z - mu) * rstd * g1.z + b1.z)
             | ((unsigned)bfbits((xv[i+1].w - mu) * rstd * g1.w + b1.w) << 16);
        *reinterpret_cast<uint4*>(dst + i * 4) = pk;
    }
}

// ---------------- K1b: projections, persistent weight-resident blocks ----------------
// v9: block type m stages its 32KB weight ONCE (XOR-swizzled), then processes
// 4 pixel-tiles of 128 with ZERO barriers in the loop -- the staging-barrier
// convoy (grid==capacity, all blocks stall in lockstep) is gone. m==0 blocks
// also produce tri (same MFMA as before, wtb read from L2).
__global__ __launch_bounds__(256) void k_proj2(
    const bf16* __restrict__ lnb, const bf16* __restrict__ wt, const bf16* __restrict__ wtb,
    const float* __restrict__ bg,
    bf16* __restrict__ qo, bf16* __restrict__ ko, bf16* __restrict__ vo, bf16* __restrict__ go,
    float* __restrict__ tri)
{
    __shared__ __align__(16) char Wl[32768];
    const int t = threadIdx.x;
    const int wv = t >> 6, lane = t & 63, g = lane >> 4, c = lane & 15;
    const int m = blockIdx.x & 3, grp = blockIdx.x >> 2;

    // stage weight matrix m: 8 uint4/thread, XOR-swizzled dest
    const uint4* Ws = reinterpret_cast<const uint4*>(wt + m * 16384);
#pragma unroll
    for (int j = 0; j < 8; j++) {
        int bb = t * 128 + j * 16;
        int bs = bb ^ (((bb >> 8) & 7) << 4);
        *reinterpret_cast<uint4*>(Wl + bs) = Ws[t * 8 + j];
    }
    __syncthreads();   // the ONLY barrier

    bf16* O = (m == 0) ? qo : (m == 1) ? ko : (m == 2) ? vo : go;
    fv4 zero = {0.f, 0.f, 0.f, 0.f};

#pragma unroll 1
    for (int j = 0; j < 4; j++) {
        const size_t pb = (size_t)(grp * 4 + j) * 128;

        // pixel fragments from global bf16 LN buffer
        bfv8 bx[2][4];
#pragma unroll
        for (int tile = 0; tile < 2; tile++)
#pragma unroll
            for (int kc = 0; kc < 4; kc++)
                bx[tile][kc] = *reinterpret_cast<const bfv8*>(
                    lnb + (pb + wv * 32 + tile * 16 + c) * CC + kc * 32 + 8 * g);

        // tri bias (m==0 blocks only): A=pixels, B=w_bias^T
        if (m == 0) {
            fv4 at0 = zero, at1 = zero;
#pragma unroll
            for (int kc = 0; kc < 4; kc++) {
                bfv8 bb = *reinterpret_cast<const bfv8*>(wtb + c * 128 + kc * 32 + 8 * g);
                at0 = __builtin_amdgcn_mfma_f32_16x16x32_bf16(bx[0][kc], bb, at0, 0, 0, 0);
                at1 = __builtin_amdgcn_mfma_f32_16x16x32_bf16(bx[1][kc], bb, at1, 0, 0, 0);
            }
            if (c < HH) {
                float4 s0 = {at0[0], at0[1], at0[2], at0[3]};
                float4 s1 = {at1[0], at1[1], at1[2], at1[3]};
                float* tb = tri + (size_t)c * NP + pb + wv * 32 + 4 * g;
                *reinterpret_cast<float4*>(tb)      = s0;
                *reinterpret_cast<float4*>(tb + 16) = s1;
            }
        }

        fv4 acc[2][8];
#pragma unroll
        for (int n = 0; n < 8; n++) { acc[0][n] = zero; acc[1][n] = zero; }
#pragma unroll
        for (int n = 0; n < 8; n++)
#pragma unroll
            for (int kc = 0; kc < 4; kc++) {
                const int row = n * 16 + c;
                const int boff = (row * 256 + kc * 64 + g * 16) ^ ((c & 7) << 4);
                bfv8 bw = *reinterpret_cast<const bfv8*>(Wl + boff);
                acc[0][n] = __builtin_amdgcn_mfma_f32_16x16x32_bf16(bw, bx[0][kc], acc[0][n], 0, 0, 0);
                acc[1][n] = __builtin_amdgcn_mfma_f32_16x16x32_bf16(bw, bx[1][kc], acc[1][n], 0, 0, 0);
            }
        if (m == 3) {
#pragma unroll
            for (int n = 0; n < 8; n++) {
                float4 bgv = *reinterpret_cast<const float4*>(bg + n * 16 + 4 * g);
                float bgs[4] = {bgv.x, bgv.y, bgv.z, bgv.w};
#pragma unroll
                for (int tile = 0; tile < 2; tile++)
#pragma unroll
                    for (int r = 0; r < 4; r++) {
                        float z = acc[tile][n][r] + bgs[r];
                        acc[tile][n][r] = 1.f / (1.f + __expf(-z));
                    }
            }
        }
#pragma unroll
        for (int tile = 0; tile < 2; tile++)
#pragma unroll
            for (int n = 0; n < 8; n++) {
                uint2 pk;
                pk.x = (unsigned)bfbits(acc[tile][n][0]) | ((unsigned)bfbits(acc[tile][n][1]) << 16);
                pk.y = (unsigned)bfbits(acc[tile][n][2]) | ((unsigned)bfbits(acc[tile][n][3]) << 16);
                *reinterpret_cast<uint2*>(O + (pb + wv * 32 + tile * 16 + c) * HC + n * 16 + 4 * g) = pk;
            }
    }
}

// ---------------- K2: flash MFMA attention (v8, unchanged) ----------------
__global__ __launch_bounds__(256) void k_attn(
    const bf16* __restrict__ qi, const bf16* __restrict__ ki, const bf16* __restrict__ vi,
    const bf16* __restrict__ gi, const float* __restrict__ mask, const float* __restrict__ tri,
    bf16* __restrict__ oo)
{
    __shared__ __align__(16) unsigned VtW[32 * 164];   // 20992 B, V^T pair-packed
    __shared__ __align__(16) unsigned Kw[320 * 20];    // 25600 B, K rows, 80B stride
    __shared__ __align__(16) float    Mw[320];         // 1280 B, mask row

    const int t = threadIdx.x;
    const int w = t >> 6, lane = t & 63, g = lane >> 4, c = lane & 15;

    const int ihh = blockIdx.x;          // 1280 blocks; 1280%8==0 spreads XCDs evenly
    const int h = ihh & 3, i = ihh >> 2;
    const size_t rowbase = (size_t)i * NN;
    const float* maskrow = mask + (size_t)i * NN;

    // ---- stage K: 320 rows x 64B, raw copy at 80B stride (1280 uint4) ----
#pragma unroll
    for (int it = 0; it < 5; it++) {
        int idx = it * 256 + t;
        int key = idx >> 2, oct = idx & 3;
        uint4 kv = *reinterpret_cast<const uint4*>(ki + (rowbase + key) * HC + h * CHD + oct * 8);
        *reinterpret_cast<uint4*>(&Kw[key * 20 + oct * 4]) = kv;
    }

    // ---- stage V^T: thread = (key-pair, d-octet), packed pair words ----
#pragma unroll
    for (int it = 0; it < 3; it++) {
        int idx = it * 256 + t;
        if (idx < 640) {
            int kp = idx >> 2, oct = idx & 3, d0 = oct * 8;
            const uint4 va = *reinterpret_cast<const uint4*>(vi + (rowbase + 2 * kp) * HC + h * CHD + d0);
            const uint4 vb = *reinterpret_cast<const uint4*>(vi + (rowbase + 2 * kp + 1) * HC + h * CHD + d0);
            unsigned a4[4] = {va.x, va.y, va.z, va.w};
            unsigned b4[4] = {vb.x, vb.y, vb.z, vb.w};
#pragma unroll
            for (int u2 = 0; u2 < 4; u2++) {
                int d_e = d0 + 2 * u2, d_o = d_e + 1;
                VtW[d_e * 164 + kp] = (a4[u2] & 0xffffu) | ((b4[u2] & 0xffffu) << 16);
                VtW[d_o * 164 + kp] = (a4[u2] >> 16)     | ((b4[u2] >> 16) << 16);
            }
        }
    }

    // ---- stage mask row (80 float4) ----
    if (t < 80)
        reinterpret_cast<float4*>(Mw)[t] = reinterpret_cast<const float4*>(maskrow)[t];

    __syncthreads();

    const unsigned* Vr0 = &VtW[c * 164];
    const unsigned* Vr1 = &VtW[(16 + c) * 164];
    const unsigned* Kl  = &Kw[c * 20 + 4 * g];   // + key*20 words per tile
    fv4 zero = {0.f, 0.f, 0.f, 0.f};

#pragma unroll 1
    for (int qt = 0; qt < 5; qt++) {
        const int qb = qt * 64 + w * 16;
        const float* trirow = tri + (size_t)h * NP + (size_t)(qb + c) * NN;
        const size_t obase  = (rowbase + qb + c) * HC + h * CHD;

        bfv8 bq = *reinterpret_cast<const bfv8*>(qi + (rowbase + qb + c) * HC + h * CHD + 8 * g);
        uint2 gg0 = *reinterpret_cast<const uint2*>(gi + obase + 4 * g);
        uint2 gg1 = *reinterpret_cast<const uint2*>(gi + obase + 16 + 4 * g);

        fv4 oa[5], ob[5];
        float mch[5], lsch[5];

        // prefetch chunk-0 tri
        float4 trC[4];
#pragma unroll
        for (int tl = 0; tl < 4; tl++)
            trC[tl] = *reinterpret_cast<const float4*>(trirow + tl * 16 + 4 * g);

#pragma unroll
        for (int ch = 0; ch < 5; ch++) {
            const int kb = ch * 64;

            // ---- prefetch next chunk's tri (only rotating stream: 16 regs) ----
            float4 trN[4];
            if (ch < 4) {
#pragma unroll
                for (int tl = 0; tl < 4; tl++)
                    trN[tl] = *reinterpret_cast<const float4*>(trirow + kb + 64 + tl * 16 + 4 * g);
            }

            // ---- K frags from LDS, mask from LDS (broadcast across c) ----
            bfv8 ak[4]; float4 mk[4];
#pragma unroll
            for (int tl = 0; tl < 4; tl++) {
                ak[tl] = *reinterpret_cast<const bfv8*>(Kl + (kb + tl * 16) * 20);
                mk[tl] = *reinterpret_cast<const float4*>(&Mw[kb + tl * 16 + 4 * g]);
            }

            // ---- QK^T ----
            fv4 sa[4];
#pragma unroll
            for (int tl = 0; tl < 4; tl++)
                sa[tl] = __builtin_amdgcn_mfma_f32_16x16x32_bf16(ak[tl], bq, zero, 0, 0, 0);

            float s[4][4];
#pragma unroll
            for (int tl = 0; tl < 4; tl++) {
                s[tl][0] = sa[tl][0] + trC[tl].x + fmaf(1.0e9f, mk[tl].x, -1.0e9f);
                s[tl][1] = sa[tl][1] + trC[tl].y + fmaf(1.0e9f, mk[tl].y, -1.0e9f);
                s[tl][2] = sa[tl][2] + trC[tl].z + fmaf(1.0e9f, mk[tl].z, -1.0e9f);
                s[tl][3] = sa[tl][3] + trC[tl].w + fmaf(1.0e9f, mk[tl].w, -1.0e9f);
            }

            // ---- chunk-local max: per-lane tree, then 2 cross-lane ----
            float m01 = fmaxf(fmaxf(s[0][0], s[0][1]), fmaxf(s[0][2], s[0][3]));
            float m23 = fmaxf(fmaxf(s[1][0], s[1][1]), fmaxf(s[1][2], s[1][3]));
            float m45 = fmaxf(fmaxf(s[2][0], s[2][1]), fmaxf(s[2][2], s[2][3]));
            float m67 = fmaxf(fmaxf(s[3][0], s[3][1]), fmaxf(s[3][2], s[3][3]));
            float mt = fmaxf(fmaxf(m01, m23), fmaxf(m45, m67));
            mt = fmaxf(mt, __shfl_xor(mt, 16, 64));
            mt = fmaxf(mt, __shfl_xor(mt, 32, 64));
            mch[ch] = mt;

            // ---- chunk-local softmax numerators ----
            float ls = 0.f;
            unsigned pw[4][2];
#pragma unroll
            for (int tl = 0; tl < 4; tl++) {
                float p0 = __expf(s[tl][0] - mt);
                float p1 = __expf(s[tl][1] - mt);
                float p2 = __expf(s[tl][2] - mt);
                float p3 = __expf(s[tl][3] - mt);
                ls += (p0 + p1) + (p2 + p3);
                pw[tl][0] = (unsigned)bfbits(p0) | ((unsigned)bfbits(p1) << 16);
                pw[tl][1] = (unsigned)bfbits(p2) | ((unsigned)bfbits(p3) << 16);
            }
            lsch[ch] = ls;

            // ---- PV into this chunk's own accumulators ----
            fv4 t0 = zero, t1 = zero;
#pragma unroll
            for (int tl = 0; tl < 4; tl++) {
                union { uint2 u; bsv4 v; } a0u, a1u, pku;
                a0u.u = *reinterpret_cast<const uint2*>(Vr0 + (kb + tl * 16) / 2 + 2 * g);
                a1u.u = *reinterpret_cast<const uint2*>(Vr1 + (kb + tl * 16) / 2 + 2 * g);
                pku.u.x = pw[tl][0]; pku.u.y = pw[tl][1];
                t0 = mfma16x16x16(a0u.v, pku.v, t0);
                t1 = mfma16x16x16(a1u.v, pku.v, t1);
            }
            oa[ch] = t0; ob[ch] = t1;

            // rotate tri prefetch
            if (ch < 4) {
#pragma unroll
                for (int tl = 0; tl < 4; tl++) trC[tl] = trN[tl];
            }
        }

        // ---- combine chunks (scalar work first; accumulators untouched) ----
        float mstar = fmaxf(fmaxf(fmaxf(mch[0], mch[1]), fmaxf(mch[2], mch[3])), mch[4]);
        float e0 = __expf(mch[0] - mstar);
        float e1 = __expf(mch[1] - mstar);
        float e2 = __expf(mch[2] - mstar);
        float e3 = __expf(mch[3] - mstar);
        float e4 = __expf(mch[4] - mstar);
        float sum = lsch[0] * e0 + lsch[1] * e1 + lsch[2] * e2 + lsch[3] * e3 + lsch[4] * e4;
        sum += __shfl_xor(sum, 16, 64);
        sum += __shfl_xor(sum, 32, 64);
        float linv = 1.f / sum;

        // hazard guard: pins every accumulator read AFTER the s_nops
        asm volatile("s_nop 7\n\ts_nop 7"
            : "+v"(oa[0]), "+v"(oa[1]), "+v"(oa[2]), "+v"(oa[3]), "+v"(oa[4]),
              "+v"(ob[0]), "+v"(ob[1]), "+v"(ob[2]), "+v"(ob[3]), "+v"(ob[4]));

        fv4 o0, o1;
#pragma unroll
        for (int r = 0; r < 4; r++) {
            o0[r] = ((oa[0][r] * e0 + oa[1][r] * e1) + (oa[2][r] * e2 + oa[3][r] * e3)) + oa[4][r] * e4;
            o1[r] = ((ob[0][r] * e0 + ob[1][r] * e1) + (ob[2][r] * e2 + ob[3][r] * e3)) + ob[4][r] * e4;
        }

#pragma unroll
        for (int mt2 = 0; mt2 < 2; mt2++) {
            fv4 oc = mt2 ? o1 : o0;
            uint2 gg = mt2 ? gg1 : gg0;
            int d0 = mt2 * 16 + 4 * g;
            float gf0 = __uint_as_float(gg.x << 16);
            float gf1 = __uint_as_float(gg.x & 0xffff0000u);
            float gf2 = __uint_as_float(gg.y << 16);
            float gf3 = __uint_as_float(gg.y & 0xffff0000u);
            uint2 st;
            st.x = (unsigned)bfbits(oc[0] * linv * gf0) | ((unsigned)bfbits(oc[1] * linv * gf1) << 16);
            st.y = (unsigned)bfbits(oc[2] * linv * gf2) | ((unsigned)bfbits(oc[3] * linv * gf3) << 16);
            *reinterpret_cast<uint2*>(oo + obase + d0) = st;
        }
    }
}

// ---------------- K3: output projection, persistent weight-resident ----------------
// v9: 400 blocks stage wot ONCE, then 4 tiles of 64 pixels each, no barriers
// in the loop.
__global__ __launch_bounds__(256) void k_out2(
    const bf16* __restrict__ oi, const bf16* __restrict__ wot, const float* __restrict__ bo,
    float* __restrict__ outp)
{
    __shared__ __align__(16) char Wl[32768];
    const int t = threadIdx.x;
    const int wv = t >> 6, lane = t & 63, g = lane >> 4, c = lane & 15;

    // stage wot (32 KB): 8 uint4/thread, XOR-swizzled dest
    const uint4* Ws = reinterpret_cast<const uint4*>(wot);
#pragma unroll
    for (int j = 0; j < 8; j++) {
        int bb = t * 128 + j * 16;
        int bs = bb ^ (((bb >> 8) & 7) << 4);
        *reinterpret_cast<uint4*>(Wl + bs) = Ws[t * 8 + j];
    }
    __syncthreads();   // the ONLY barrier

    fv4 zero = {0.f, 0.f, 0.f, 0.f};

#pragma unroll 1
    for (int j = 0; j < 4; j++) {
        const size_t pb = (size_t)(blockIdx.x * 4 + j) * 64;

        bfv8 bx[4];
#pragma unroll
        for (int kc = 0; kc < 4; kc++)
            bx[kc] = *reinterpret_cast<const bfv8*>(oi + (pb + wv * 16 + c) * HC + kc * 32 + 8 * g);

        fv4 acc[8];
#pragma unroll
        for (int n = 0; n < 8; n++) acc[n] = zero;
#pragma unroll
        for (int n = 0; n < 8; n++)
#pragma unroll
            for (int kc = 0; kc < 4; kc++) {
                const int row = n * 16 + c;
                const int boff = (row * 256 + kc * 64 + g * 16) ^ ((c & 7) << 4);
                bfv8 bw = *reinterpret_cast<const bfv8*>(Wl + boff);
                acc[n] = __builtin_amdgcn_mfma_f32_16x16x32_bf16(bw, bx[kc], acc[n], 0, 0, 0);
            }
#pragma unroll
        for (int n = 0; n < 8; n++) {
            float4 b4 = *reinterpret_cast<const float4*>(bo + n * 16 + 4 * g);
            float4 st;
            st.x = acc[n][0] + b4.x;
            st.y = acc[n][1] + b4.y;
            st.z = acc[n][2] + b4.z;
            st.w = acc[n][3] + b4.w;
            *reinterpret_cast<float4*>(outp + (pb + wv * 16 + c) * CC + n * 16 + 4 * g) = st;
        }
    }
}

extern "C" void kernel_launch(void* const* d_in, const int* in_sizes, int n_in,
                              void* d_out, int out_size, void* d_ws, size_t ws_size,
                              hipStream_t stream) {
    const float* x      = (const float*)d_in[0];
    const float* mask   = (const float*)d_in[1];
    const float* ln_g   = (const float*)d_in[2];
    const float* ln_b   = (const float*)d_in[3];
    const float* w_bias = (const float*)d_in[4];
    const float* wq     = (const float*)d_in[5];
    const float* wk     = (const float*)d_in[6];
    const float* wv     = (const float*)d_in[7];
    const float* wg     = (const float*)d_in[8];
    const float* bg     = (const float*)d_in[9];
    const float* wo     = (const float*)d_in[10];
    const float* bo     = (const float*)d_in[11];
    float* outp = (float*)d_out;

    bf16* qws = (bf16*)d_ws;
    bf16* kws = qws + (size_t)NP*HC;
    bf16* vws = kws + (size_t)NP*HC;
    bf16* gws = vws + (size_t)NP*HC;
    bf16* ows = gws + (size_t)NP*HC;
    float* tri = (float*)(ows + (size_t)NP*HC);
    bf16* wt  = (bf16*)(tri + (size_t)NP*HH);
    bf16* wot = wt + 4 * 16384;
    bf16* wtb = wot + 16384;
    bf16* lnb = wtb + 2048;

    hipLaunchKernelGGL(k_wconv, dim3(6), dim3(256), 0, stream,
                       wq, wk, wv, wg, wo, w_bias, wt, wot, wtb);
    hipLaunchKernelGGL(k_ln, dim3(NP/64), dim3(256), 0, stream,
                       x, ln_g, ln_b, lnb);
    hipLaunchKernelGGL(k_proj2, dim3(800), dim3(256), 0, stream,
                       lnb, wt, wtb, bg, qws, kws, vws, gws, tri);
    hipLaunchKernelGGL(k_attn, dim3(NN*HH), dim3(256), 0, stream,
                       qws, kws, vws, gws, mask, tri, ows);
    hipLaunchKernelGGL(k_out2, dim3(400), dim3(256), 0, stream,
                       ows, wot, bo, outp);
}

// Round 10
// 297.255 us; speedup vs baseline: 1.1042x; 1.1042x over previous
//
#include <hip/hip_runtime.h>
#include <hip/hip_bf16.h>

#define NN 320
#define CC 128
#define HH 4
#define CHD 32
#define HC 128
#define NP (NN*NN)

typedef __hip_bfloat16 bf16;
typedef __bf16 bfv8 __attribute__((ext_vector_type(8)));
typedef short bsv4 __attribute__((ext_vector_type(4)));
typedef float fv4 __attribute__((ext_vector_type(4)));

__device__ __forceinline__ unsigned short bfbits(float f) {
    bf16 h = __float2bfloat16(f);
    return *reinterpret_cast<unsigned short*>(&h);
}

// 16x16x16 bf16 MFMA (K=16): B-frag layout B[k=4g+i][n=c] matches the QK
// D-layout S[k=4g+r][q=c] exactly -> P feeds PV straight from registers.
// NOTE: inline asm => LLVM's hazard recognizer cannot guard the dest; any
// VALU read of the accumulator must be pinned behind an s_nop guard.
__device__ __forceinline__ fv4 mfma16x16x16(bsv4 a, bsv4 b, fv4 c) {
    asm("v_mfma_f32_16x16x16_bf16 %0, %1, %2, %0" : "+v"(c) : "v"(a), "v"(b));
    return c;
}

// ---------------- K0: weight convert/transpose to bf16 ----------------
__global__ __launch_bounds__(256) void k_wconv(
    const float* __restrict__ wq, const float* __restrict__ wk,
    const float* __restrict__ wv, const float* __restrict__ wg,
    const float* __restrict__ wo, const float* __restrict__ w_bias,
    bf16* __restrict__ wt, bf16* __restrict__ wot, bf16* __restrict__ wtb)
{
    __shared__ unsigned short T[128 * 136];
    const int b = blockIdx.x, t = threadIdx.x;
    if (b < 5) {
        const float* W = (b == 0) ? wq : (b == 1) ? wk : (b == 2) ? wv : (b == 3) ? wg : wo;
        bf16* D = (b < 4) ? (wt + b * 16384) : wot;
        const float scale = (b == 0) ? 0.17677669529663687f : 1.0f;
        for (int idx = t; idx < 16384; idx += 256) {
            int c = idx >> 7, out = idx & 127;
            T[out * 136 + c] = bfbits(W[idx] * scale);
        }
        __syncthreads();
        for (int i8 = t; i8 < 2048; i8 += 256) {
            int out = i8 >> 4, c0 = (i8 & 15) * 8;
            uint4 v = *reinterpret_cast<const uint4*>(&T[out * 136 + c0]);
            *reinterpret_cast<uint4*>(D + out * 128 + c0) = v;
        }
    } else {
        int out = t >> 4, c0 = (t & 15) * 8;
        unsigned short vals[8];
#pragma unroll
        for (int j = 0; j < 8; j++)
            vals[j] = (out < 4) ? bfbits(w_bias[(c0 + j) * 4 + out]) : (unsigned short)0;
        *reinterpret_cast<uint4*>(wtb + out * 128 + c0) = *reinterpret_cast<uint4*>(vals);
    }
}

// ---------------- K1: LN + MFMA projections + tri_bias (v6/v8 version) ----------------
__global__ __launch_bounds__(256) void k_proj(
    const float* __restrict__ x, const float* __restrict__ ln_g, const float* __restrict__ ln_b,
    const bf16* __restrict__ wt, const bf16* __restrict__ wtb, const float* __restrict__ bg,
    bf16* __restrict__ qo, bf16* __restrict__ ko, bf16* __restrict__ vo, bf16* __restrict__ go,
    float* __restrict__ tri)
{
    __shared__ __align__(16) unsigned short A[128 * 136];   // LN(x) bf16 tile, then weight buffer
    const int t = threadIdx.x;
    const int wv = t >> 6, lane = t & 63, g = lane >> 4, c = lane & 15;
    const size_t pb = (size_t)blockIdx.x * 128;

    // ---- LayerNorm in registers: 4 threads per pixel, 2 rounds ----
#pragma unroll
    for (int rnd = 0; rnd < 2; rnd++) {
        const int p = (t >> 2) + rnd * 64, l = t & 3;
        const float* xr = x + (pb + p) * CC + l * 32;
        float4 xv[8];
#pragma unroll
        for (int i = 0; i < 8; i++) xv[i] = reinterpret_cast<const float4*>(xr)[i];
        float s = 0.f, s2 = 0.f;
#pragma unroll
        for (int i = 0; i < 8; i++) {
            s  += xv[i].x + xv[i].y + xv[i].z + xv[i].w;
            s2 += xv[i].x * xv[i].x + xv[i].y * xv[i].y + xv[i].z * xv[i].z + xv[i].w * xv[i].w;
        }
        s  += __shfl_xor(s, 1, 4);  s  += __shfl_xor(s, 2, 4);
        s2 += __shfl_xor(s2, 1, 4); s2 += __shfl_xor(s2, 2, 4);
        float mu = s * (1.f / CC);
        float var = s2 * (1.f / CC) - mu * mu;
        float rstd = rsqrtf(var + 1e-5f);
        const float4* gr = reinterpret_cast<const float4*>(ln_g + l * 32);
        const float4* br = reinterpret_cast<const float4*>(ln_b + l * 32);
#pragma unroll
        for (int i = 0; i < 8; i += 2) {
            float4 g0 = gr[i], g1 = gr[i + 1], b0 = br[i], b1 = br[i + 1];
            uint4 pk;
            pk.x = (unsigned)bfbits((xv[i].x - mu) * rstd * g0.x + b0.x)
                 | ((unsigned)bfbits((xv[i].y - mu) * rstd * g0.y + b0.y) << 16);
            pk.y = (unsigned)bfbits((xv[i].z - mu) * rstd * g0.z + b0.z)
                 | ((unsigned)bfbits((xv[i].w - mu) * rstd * g0.w + b0.w) << 16);
            pk.z = (unsigned)bfbits((xv[i+1].x - mu) * rstd * g1.x + b1.x)
                 | ((unsigned)bfbits((xv[i+1].y - mu) * rstd * g1.y + b1.y) << 16);
            pk.w = (unsigned)bfbits((xv[i+1].z - mu) * rstd * g1.z + b1.z)
                 | ((unsigned)bfbits((xv[i+1].w - mu) * rstd * g1.w + b1.w) << 16);
            *reinterpret_cast<uint4*>(&A[p * 136 + l * 32 + i * 4]) = pk;
        }
    }
    __syncthreads();

    // ---- pixel fragments: 2 tiles of 16 pixels per wave ----
    bfv8 bx[2][4];
#pragma unroll
    for (int tile = 0; tile < 2; tile++)
#pragma unroll
        for (int kc = 0; kc < 4; kc++)
            bx[tile][kc] = *reinterpret_cast<const bfv8*>(
                &A[(wv * 32 + tile * 16 + c) * 136 + kc * 32 + 8 * g]);

    fv4 zero = {0.f, 0.f, 0.f, 0.f};

    // ---- tri bias: A=pixels, B=w_bias^T (D col = head) ----
    {
        fv4 at0 = zero, at1 = zero;
#pragma unroll
        for (int kc = 0; kc < 4; kc++) {
            bfv8 bb = *reinterpret_cast<const bfv8*>(wtb + c * 128 + kc * 32 + 8 * g);
            at0 = __builtin_amdgcn_mfma_f32_16x16x32_bf16(bx[0][kc], bb, at0, 0, 0, 0);
            at1 = __builtin_amdgcn_mfma_f32_16x16x32_bf16(bx[1][kc], bb, at1, 0, 0, 0);
        }
        if (c < HH) {
            float4 s0 = {at0[0], at0[1], at0[2], at0[3]};
            float4 s1 = {at1[0], at1[1], at1[2], at1[3]};
            float* tb = tri + (size_t)c * NP + pb + wv * 32 + 4 * g;
            *reinterpret_cast<float4*>(tb)      = s0;
            *reinterpret_cast<float4*>(tb + 16) = s1;
        }
    }

    __syncthreads();   // A's LN tile fully consumed -> safe to overwrite with weights

    // ---- q,k,v,g projections: weights staged in LDS, shared by all waves ----
    char* Wl = reinterpret_cast<char*>(A);
    bf16* Os[4] = {qo, ko, vo, go};
#pragma unroll 1
    for (int m = 0; m < 4; m++) {
        // stage 32 KB: 8 uint4/thread, XOR-swizzled dest (involution per 16B granule)
        const uint4* Ws = reinterpret_cast<const uint4*>(wt + m * 16384);
#pragma unroll
        for (int j = 0; j < 8; j++) {
            int bb = t * 128 + j * 16;
            int bs = bb ^ (((bb >> 8) & 7) << 4);
            *reinterpret_cast<uint4*>(Wl + bs) = Ws[t * 8 + j];
        }
        __syncthreads();

        fv4 acc[2][8];
#pragma unroll
        for (int n = 0; n < 8; n++) { acc[0][n] = zero; acc[1][n] = zero; }
#pragma unroll
        for (int n = 0; n < 8; n++)
#pragma unroll
            for (int kc = 0; kc < 4; kc++) {
                const int row = n * 16 + c;
                const int boff = (row * 256 + kc * 64 + g * 16) ^ ((c & 7) << 4);
                bfv8 bw = *reinterpret_cast<const bfv8*>(Wl + boff);
                acc[0][n] = __builtin_amdgcn_mfma_f32_16x16x32_bf16(bw, bx[0][kc], acc[0][n], 0, 0, 0);
                acc[1][n] = __builtin_amdgcn_mfma_f32_16x16x32_bf16(bw, bx[1][kc], acc[1][n], 0, 0, 0);
            }
        if (m == 3) {
#pragma unroll
            for (int n = 0; n < 8; n++) {
                float4 bgv = *reinterpret_cast<const float4*>(bg + n * 16 + 4 * g);
                float bgs[4] = {bgv.x, bgv.y, bgv.z, bgv.w};
#pragma unroll
                for (int tile = 0; tile < 2; tile++)
#pragma unroll
                    for (int r = 0; r < 4; r++) {
                        float z = acc[tile][n][r] + bgs[r];
                        acc[tile][n][r] = 1.f / (1.f + __expf(-z));
                    }
            }
        }
        bf16* O = Os[m];
#pragma unroll
        for (int tile = 0; tile < 2; tile++)
#pragma unroll
            for (int n = 0; n < 8; n++) {
                uint2 pk;
                pk.x = (unsigned)bfbits(acc[tile][n][0]) | ((unsigned)bfbits(acc[tile][n][1]) << 16);
                pk.y = (unsigned)bfbits(acc[tile][n][2]) | ((unsigned)bfbits(acc[tile][n][3]) << 16);
                *reinterpret_cast<uint2*>(O + (pb + wv * 32 + tile * 16 + c) * HC + n * 16 + 4 * g) = pk;
            }
        __syncthreads();   // all reads of Wl done before next m overwrites
    }
}

// ---------------- K2: flash MFMA attention (v8 + setprio + qt-ahead prefetch) ----------------
// v10: (a) s_setprio(1) around QK/PV MFMA clusters (T5: attn +4-7%, m191);
// (b) q/gate for qt+1 prefetched at qt start (8 VGPR rotation; hides ~900cy
// HBM latency under the 5-chunk compute). Everything else byte-identical v8.
__global__ __launch_bounds__(256) void k_attn(
    const bf16* __restrict__ qi, const bf16* __restrict__ ki, const bf16* __restrict__ vi,
    const bf16* __restrict__ gi, const float* __restrict__ mask, const float* __restrict__ tri,
    bf16* __restrict__ oo)
{
    __shared__ __align__(16) unsigned VtW[32 * 164];   // 20992 B, V^T pair-packed
    __shared__ __align__(16) unsigned Kw[320 * 20];    // 25600 B, K rows, 80B stride
    __shared__ __align__(16) float    Mw[320];         // 1280 B, mask row

    const int t = threadIdx.x;
    const int w = t >> 6, lane = t & 63, g = lane >> 4, c = lane & 15;

    const int ihh = blockIdx.x;          // 1280 blocks; 1280%8==0 spreads XCDs evenly
    const int h = ihh & 3, i = ihh >> 2;
    const size_t rowbase = (size_t)i * NN;
    const float* maskrow = mask + (size_t)i * NN;

    // ---- stage K: 320 rows x 64B, raw copy at 80B stride (1280 uint4) ----
#pragma unroll
    for (int it = 0; it < 5; it++) {
        int idx = it * 256 + t;
        int key = idx >> 2, oct = idx & 3;
        uint4 kv = *reinterpret_cast<const uint4*>(ki + (rowbase + key) * HC + h * CHD + oct * 8);
        *reinterpret_cast<uint4*>(&Kw[key * 20 + oct * 4]) = kv;
    }

    // ---- stage V^T: thread = (key-pair, d-octet), packed pair words ----
#pragma unroll
    for (int it = 0; it < 3; it++) {
        int idx = it * 256 + t;
        if (idx < 640) {
            int kp = idx >> 2, oct = idx & 3, d0 = oct * 8;
            const uint4 va = *reinterpret_cast<const uint4*>(vi + (rowbase + 2 * kp) * HC + h * CHD + d0);
            const uint4 vb = *reinterpret_cast<const uint4*>(vi + (rowbase + 2 * kp + 1) * HC + h * CHD + d0);
            unsigned a4[4] = {va.x, va.y, va.z, va.w};
            unsigned b4[4] = {vb.x, vb.y, vb.z, vb.w};
#pragma unroll
            for (int u2 = 0; u2 < 4; u2++) {
                int d_e = d0 + 2 * u2, d_o = d_e + 1;
                VtW[d_e * 164 + kp] = (a4[u2] & 0xffffu) | ((b4[u2] & 0xffffu) << 16);
                VtW[d_o * 164 + kp] = (a4[u2] >> 16)     | ((b4[u2] >> 16) << 16);
            }
        }
    }

    // ---- stage mask row (80 float4) ----
    if (t < 80)
        reinterpret_cast<float4*>(Mw)[t] = reinterpret_cast<const float4*>(maskrow)[t];

    __syncthreads();

    const unsigned* Vr0 = &VtW[c * 164];
    const unsigned* Vr1 = &VtW[(16 + c) * 164];
    const unsigned* Kl  = &Kw[c * 20 + 4 * g];   // + key*20 words per tile
    fv4 zero = {0.f, 0.f, 0.f, 0.f};

    // ---- qt=0 q/gate prefetch ----
    const int qb0 = w * 16;
    bfv8 bqC = *reinterpret_cast<const bfv8*>(qi + (rowbase + qb0 + c) * HC + h * CHD + 8 * g);
    uint2 ggA0 = *reinterpret_cast<const uint2*>(gi + (rowbase + qb0 + c) * HC + h * CHD + 4 * g);
    uint2 ggA1 = *reinterpret_cast<const uint2*>(gi + (rowbase + qb0 + c) * HC + h * CHD + 16 + 4 * g);

#pragma unroll 1
    for (int qt = 0; qt < 5; qt++) {
        const int qb = qt * 64 + w * 16;
        const float* trirow = tri + (size_t)h * NP + (size_t)(qb + c) * NN;
        const size_t obase  = (rowbase + qb + c) * HC + h * CHD;

        // ---- issue qt+1 q/gate loads now; consumed at rotation (end of body) ----
        bfv8 bqN; uint2 ggN0, ggN1;
        if (qt < 4) {
            const size_t nbase = (rowbase + qb + 64 + c) * HC + h * CHD;
            bqN  = *reinterpret_cast<const bfv8*>(qi + nbase + 8 * g);
            ggN0 = *reinterpret_cast<const uint2*>(gi + nbase + 4 * g);
            ggN1 = *reinterpret_cast<const uint2*>(gi + nbase + 16 + 4 * g);
        }

        fv4 oa[5], ob[5];
        float mch[5], lsch[5];

        // prefetch chunk-0 tri
        float4 trC[4];
#pragma unroll
        for (int tl = 0; tl < 4; tl++)
            trC[tl] = *reinterpret_cast<const float4*>(trirow + tl * 16 + 4 * g);

#pragma unroll
        for (int ch = 0; ch < 5; ch++) {
            const int kb = ch * 64;

            // ---- prefetch next chunk's tri (only rotating stream: 16 regs) ----
            float4 trN[4];
            if (ch < 4) {
#pragma unroll
                for (int tl = 0; tl < 4; tl++)
                    trN[tl] = *reinterpret_cast<const float4*>(trirow + kb + 64 + tl * 16 + 4 * g);
            }

            // ---- K frags from LDS, mask from LDS (broadcast across c) ----
            bfv8 ak[4]; float4 mk[4];
#pragma unroll
            for (int tl = 0; tl < 4; tl++) {
                ak[tl] = *reinterpret_cast<const bfv8*>(Kl + (kb + tl * 16) * 20);
                mk[tl] = *reinterpret_cast<const float4*>(&Mw[kb + tl * 16 + 4 * g]);
            }

            // ---- QK^T (setprio: keep matrix pipe fed vs other waves' loads) ----
            fv4 sa[4];
            __builtin_amdgcn_s_setprio(1);
#pragma unroll
            for (int tl = 0; tl < 4; tl++)
                sa[tl] = __builtin_amdgcn_mfma_f32_16x16x32_bf16(ak[tl], bqC, zero, 0, 0, 0);
            __builtin_amdgcn_s_setprio(0);

            float s[4][4];
#pragma unroll
            for (int tl = 0; tl < 4; tl++) {
                s[tl][0] = sa[tl][0] + trC[tl].x + fmaf(1.0e9f, mk[tl].x, -1.0e9f);
                s[tl][1] = sa[tl][1] + trC[tl].y + fmaf(1.0e9f, mk[tl].y, -1.0e9f);
                s[tl][2] = sa[tl][2] + trC[tl].z + fmaf(1.0e9f, mk[tl].z, -1.0e9f);
                s[tl][3] = sa[tl][3] + trC[tl].w + fmaf(1.0e9f, mk[tl].w, -1.0e9f);
            }

            // ---- chunk-local max: per-lane tree, then 2 cross-lane ----
            float m01 = fmaxf(fmaxf(s[0][0], s[0][1]), fmaxf(s[0][2], s[0][3]));
            float m23 = fmaxf(fmaxf(s[1][0], s[1][1]), fmaxf(s[1][2], s[1][3]));
            float m45 = fmaxf(fmaxf(s[2][0], s[2][1]), fmaxf(s[2][2], s[2][3]));
            float m67 = fmaxf(fmaxf(s[3][0], s[3][1]), fmaxf(s[3][2], s[3][3]));
            float mt = fmaxf(fmaxf(m01, m23), fmaxf(m45, m67));
            mt = fmaxf(mt, __shfl_xor(mt, 16, 64));
            mt = fmaxf(mt, __shfl_xor(mt, 32, 64));
            mch[ch] = mt;

            // ---- chunk-local softmax numerators ----
            float ls = 0.f;
            unsigned pw[4][2];
#pragma unroll
            for (int tl = 0; tl < 4; tl++) {
                float p0 = __expf(s[tl][0] - mt);
                float p1 = __expf(s[tl][1] - mt);
                float p2 = __expf(s[tl][2] - mt);
                float p3 = __expf(s[tl][3] - mt);
                ls += (p0 + p1) + (p2 + p3);
                pw[tl][0] = (unsigned)bfbits(p0) | ((unsigned)bfbits(p1) << 16);
                pw[tl][1] = (unsigned)bfbits(p2) | ((unsigned)bfbits(p3) << 16);
            }
            lsch[ch] = ls;

            // ---- PV into this chunk's own accumulators ----
            fv4 t0 = zero, t1 = zero;
            __builtin_amdgcn_s_setprio(1);
#pragma unroll
            for (int tl = 0; tl < 4; tl++) {
                union { uint2 u; bsv4 v; } a0u, a1u, pku;
                a0u.u = *reinterpret_cast<const uint2*>(Vr0 + (kb + tl * 16) / 2 + 2 * g);
                a1u.u = *reinterpret_cast<const uint2*>(Vr1 + (kb + tl * 16) / 2 + 2 * g);
                pku.u.x = pw[tl][0]; pku.u.y = pw[tl][1];
                t0 = mfma16x16x16(a0u.v, pku.v, t0);
                t1 = mfma16x16x16(a1u.v, pku.v, t1);
            }
            __builtin_amdgcn_s_setprio(0);
            oa[ch] = t0; ob[ch] = t1;

            // rotate tri prefetch
            if (ch < 4) {
#pragma unroll
                for (int tl = 0; tl < 4; tl++) trC[tl] = trN[tl];
            }
        }

        // ---- combine chunks (scalar work first; accumulators untouched) ----
        float mstar = fmaxf(fmaxf(fmaxf(mch[0], mch[1]), fmaxf(mch[2], mch[3])), mch[4]);
        float e0 = __expf(mch[0] - mstar);
        float e1 = __expf(mch[1] - mstar);
        float e2 = __expf(mch[2] - mstar);
        float e3 = __expf(mch[3] - mstar);
        float e4 = __expf(mch[4] - mstar);
        float sum = lsch[0] * e0 + lsch[1] * e1 + lsch[2] * e2 + lsch[3] * e3 + lsch[4] * e4;
        sum += __shfl_xor(sum, 16, 64);
        sum += __shfl_xor(sum, 32, 64);
        float linv = 1.f / sum;

        // hazard guard: pins every accumulator read AFTER the s_nops
        asm volatile("s_nop 7\n\ts_nop 7"
            : "+v"(oa[0]), "+v"(oa[1]), "+v"(oa[2]), "+v"(oa[3]), "+v"(oa[4]),
              "+v"(ob[0]), "+v"(ob[1]), "+v"(ob[2]), "+v"(ob[3]), "+v"(ob[4]));

        fv4 o0, o1;
#pragma unroll
        for (int r = 0; r < 4; r++) {
            o0[r] = ((oa[0][r] * e0 + oa[1][r] * e1) + (oa[2][r] * e2 + oa[3][r] * e3)) + oa[4][r] * e4;
            o1[r] = ((ob[0][r] * e0 + ob[1][r] * e1) + (ob[2][r] * e2 + ob[3][r] * e3)) + ob[4][r] * e4;
        }

#pragma unroll
        for (int mt2 = 0; mt2 < 2; mt2++) {
            fv4 oc = mt2 ? o1 : o0;
            uint2 gg = mt2 ? ggA1 : ggA0;
            int d0 = mt2 * 16 + 4 * g;
            float gf0 = __uint_as_float(gg.x << 16);
            float gf1 = __uint_as_float(gg.x & 0xffff0000u);
            float gf2 = __uint_as_float(gg.y << 16);
            float gf3 = __uint_as_float(gg.y & 0xffff0000u);
            uint2 st;
            st.x = (unsigned)bfbits(oc[0] * linv * gf0) | ((unsigned)bfbits(oc[1] * linv * gf1) << 16);
            st.y = (unsigned)bfbits(oc[2] * linv * gf2) | ((unsigned)bfbits(oc[3] * linv * gf3) << 16);
            *reinterpret_cast<uint2*>(oo + obase + d0) = st;
        }

        // ---- rotate q/gate prefetch ----
        if (qt < 4) { bqC = bqN; ggA0 = ggN0; ggA1 = ggN1; }
    }
}

// ---------------- K3: MFMA output projection (wot staged in LDS, v6/v8 version) ----------------
__global__ __launch_bounds__(256) void k_out(
    const bf16* __restrict__ oi, const bf16* __restrict__ wot, const float* __restrict__ bo,
    float* __restrict__ outp)
{
    __shared__ __align__(16) char Wl[32768];
    const int t = threadIdx.x;
    const int wv = t >> 6, lane = t & 63, g = lane >> 4, c = lane & 15;
    const size_t pb = (size_t)blockIdx.x * 64;

    // issue input frag loads first so they fly during weight staging
    bfv8 bx[4];
#pragma unroll
    for (int kc = 0; kc < 4; kc++)
        bx[kc] = *reinterpret_cast<const bfv8*>(oi + (pb + wv * 16 + c) * HC + kc * 32 + 8 * g);

    // stage wot (32 KB): 8 uint4/thread, XOR-swizzled dest
    const uint4* Ws = reinterpret_cast<const uint4*>(wot);
#pragma unroll
    for (int j = 0; j < 8; j++) {
        int bb = t * 128 + j * 16;
        int bs = bb ^ (((bb >> 8) & 7) << 4);
        *reinterpret_cast<uint4*>(Wl + bs) = Ws[t * 8 + j];
    }
    __syncthreads();

    fv4 zero = {0.f, 0.f, 0.f, 0.f};
    fv4 acc[8];
#pragma unroll
    for (int n = 0; n < 8; n++) acc[n] = zero;
#pragma unroll
    for (int n = 0; n < 8; n++)
#pragma unroll
        for (int kc = 0; kc < 4; kc++) {
            const int row = n * 16 + c;
            const int boff = (row * 256 + kc * 64 + g * 16) ^ ((c & 7) << 4);
            bfv8 bw = *reinterpret_cast<const bfv8*>(Wl + boff);
            acc[n] = __builtin_amdgcn_mfma_f32_16x16x32_bf16(bw, bx[kc], acc[n], 0, 0, 0);
        }
#pragma unroll
    for (int n = 0; n < 8; n++) {
        float4 b4 = *reinterpret_cast<const float4*>(bo + n * 16 + 4 * g);
        float4 st;
        st.x = acc[n][0] + b4.x;
        st.y = acc[n][1] + b4.y;
        st.z = acc[n][2] + b4.z;
        st.w = acc[n][3] + b4.w;
        *reinterpret_cast<float4*>(outp + (pb + wv * 16 + c) * CC + n * 16 + 4 * g) = st;
    }
}

extern "C" void kernel_launch(void* const* d_in, const int* in_sizes, int n_in,
                              void* d_out, int out_size, void* d_ws, size_t ws_size,
                              hipStream_t stream) {
    const float* x      = (const float*)d_in[0];
    const float* mask   = (const float*)d_in[1];
    const float* ln_g   = (const float*)d_in[2];
    const float* ln_b   = (const float*)d_in[3];
    const float* w_bias = (const float*)d_in[4];
    const float* wq     = (const float*)d_in[5];
    const float* wk     = (const float*)d_in[6];
    const float* wv     = (const float*)d_in[7];
    const float* wg     = (const float*)d_in[8];
    const float* bg     = (const float*)d_in[9];
    const float* wo     = (const float*)d_in[10];
    const float* bo     = (const float*)d_in[11];
    float* outp = (float*)d_out;

    bf16* qws = (bf16*)d_ws;
    bf16* kws = qws + (size_t)NP*HC;
    bf16* vws = kws + (size_t)NP*HC;
    bf16* gws = vws + (size_t)NP*HC;
    bf16* ows = gws + (size_t)NP*HC;
    float* tri = (float*)(ows + (size_t)NP*HC);
    bf16* wt  = (bf16*)(tri + (size_t)NP*HH);
    bf16* wot = wt + 4 * 16384;
    bf16* wtb = wot + 16384;

    hipLaunchKernelGGL(k_wconv, dim3(6), dim3(256), 0, stream,
                       wq, wk, wv, wg, wo, w_bias, wt, wot, wtb);
    hipLaunchKernelGGL(k_proj, dim3(NP/128), dim3(256), 0, stream,
                       x, ln_g, ln_b, wt, wtb, bg, qws, kws, vws, gws, tri);
    hipLaunchKernelGGL(k_attn, dim3(NN*HH), dim3(256), 0, stream,
                       qws, kws, vws, gws, mask, tri, ows);
    hipLaunchKernelGGL(k_out, dim3(NP/64), dim3(256), 0, stream,
                       ows, wot, bo, outp);
}